// Round 3
// baseline (1235.251 us; speedup 1.0000x reference)
//
#include <hip/hip_runtime.h>
#include <cstdint>
#include <cstddef>

#define BN_EPS 1e-5f

// ---------------- helpers ----------------

__device__ inline uint16_t f2bf(float f){
  union {float f; uint32_t u;} v; v.f = f;
  uint32_t u = v.u;
  return (uint16_t)((u + 0x7FFFu + ((u >> 16) & 1u)) >> 16);
}

__device__ inline uint32_t pack2bf(float a, float b){
  return (uint32_t)f2bf(a) | ((uint32_t)f2bf(b) << 16);
}

__device__ inline void bf2f2(uint32_t w, float& a, float& b){
  union {uint32_t u; float f;} ua, ub;
  ua.u = w << 16; ub.u = w & 0xFFFF0000u;
  a = ua.f; b = ub.f;
}

// ---------------- graph preprocessing ----------------

__global__ void k_count(const int* __restrict__ col, int* __restrict__ indeg, int E){
  int e = blockIdx.x*blockDim.x + threadIdx.x;
  if (e < E) atomicAdd(&indeg[col[e]], 1);
}

// exclusive scan, 1024 elems/block
__global__ void k_scan1(const int* __restrict__ in, int* __restrict__ out, int* __restrict__ bsum, int n){
  __shared__ int s[256];
  int t = threadIdx.x;
  int base = blockIdx.x*1024 + t*4;
  int v0 = (base+0 < n) ? in[base+0] : 0;
  int v1 = (base+1 < n) ? in[base+1] : 0;
  int v2 = (base+2 < n) ? in[base+2] : 0;
  int v3 = (base+3 < n) ? in[base+3] : 0;
  int lsum = v0+v1+v2+v3;
  s[t] = lsum;
  __syncthreads();
  for (int off=1; off<256; off<<=1){
    int x = 0;
    if (t >= off) x = s[t-off];
    __syncthreads();
    if (t >= off) s[t] += x;
    __syncthreads();
  }
  int excl = s[t] - lsum;
  if (base+0 < n) out[base+0] = excl;
  if (base+1 < n) out[base+1] = excl + v0;
  if (base+2 < n) out[base+2] = excl + v0 + v1;
  if (base+3 < n) out[base+3] = excl + v0 + v1 + v2;
  if (t == 255) bsum[blockIdx.x] = s[255];
}

// exclusive scan of block sums (nblk <= 128)
__global__ void k_scan2(int* bsum, int nblk){
  __shared__ int s[128];
  int t = threadIdx.x;
  int v = (t < nblk) ? bsum[t] : 0;
  s[t] = v;
  __syncthreads();
  for (int off=1; off<128; off<<=1){
    int x = 0;
    if (t >= off) x = s[t-off];
    __syncthreads();
    if (t >= off) s[t] += x;
    __syncthreads();
  }
  if (t < nblk) bsum[t] = s[t] - v;
}

__global__ void k_scan3(int* __restrict__ out, const int* __restrict__ bsum, int n, int E){
  int i = blockIdx.x*blockDim.x + threadIdx.x;
  if (i < n) out[i] += bsum[i>>10];
  if (i == 0) out[n] = E;
}

__global__ void k_dinv(const int* __restrict__ indeg, float* __restrict__ dinv, int n){
  int i = blockIdx.x*blockDim.x + threadIdx.x;
  if (i < n) dinv[i] = 1.0f / sqrtf((float)(indeg[i] + 1));
}

__global__ void k_initbcur(const int* __restrict__ offs, int* __restrict__ bcur, int N, int nb){
  int b = blockIdx.x*blockDim.x + threadIdx.x;
  if (b < nb) bcur[b] = offs[min(b<<6, N)];
}

// pass A: scatter packed {row,col} into 64-node destination buckets
__global__ void k_passA(const int* __restrict__ row, const int* __restrict__ col,
                        int* __restrict__ bcur, uint2* __restrict__ ebuf, int E){
  int e = blockIdx.x*blockDim.x + threadIdx.x;
  if (e < E){
    int c = col[e];
    int pos = atomicAdd(&bcur[c>>6], 1);
    uint2 rc; rc.x = (unsigned)row[e]; rc.y = (unsigned)c;
    ebuf[pos] = rc;
  }
}

// pass B: per-bucket CSR fill, LDS cursors, L2-local writes
__global__ __launch_bounds__(256) void k_passB(const uint2* __restrict__ ebuf,
                                               const int* __restrict__ offs,
                                               int* __restrict__ csr, int N){
  __shared__ int cur[64];
  int b = blockIdx.x;
  int base = b << 6;
  int t = threadIdx.x;
  if (t < 64) cur[t] = offs[min(base + t, N)];
  int s = offs[min(base, N)];
  int e = offs[min(base + 64, N)];
  __syncthreads();
  for (int i = s + t; i < e; i += 256){
    uint2 rc = ebuf[i];
    int local = (int)rc.y - base;
    int pos = atomicAdd(&cur[local], 1);
    csr[pos] = (int)rc.x;
  }
}

__global__ void k_cnt(const int* __restrict__ batch, int* __restrict__ cnt, int n){
  int i = blockIdx.x*blockDim.x + threadIdx.x;
  if (i < n) atomicAdd(&cnt[batch[i]], 1);
}

// per-column bn finalize: scale = g*rstd, shift = be - mu*scale
__global__ void k_bnfin(const float* __restrict__ region, int F, float invCount,
                        const float* __restrict__ g, const float* __restrict__ be,
                        float* __restrict__ scale, float* __restrict__ shift){
  int i = blockIdx.x*blockDim.x + threadIdx.x;
  if (i >= F) return;
  float s = 0.f, q = 0.f;
  for (int sl = 0; sl < 32; sl++){
    s += region[sl*2*F + i];
    q += region[sl*2*F + F + i];
  }
  float mu  = s * invCount;
  float var = q * invCount - mu*mu;
  if (var < 0.f) var = 0.f;
  float rstd = 1.0f / sqrtf(var + BN_EPS);
  float sc = g[i] * rstd;
  scale[i] = sc;
  shift[i] = be[i] - mu * sc;
}

// xs = bf16(x * dinv[node]) : N x 64
__global__ void k_prep1(const float4* __restrict__ x, const float* __restrict__ dinv,
                        ushort4* __restrict__ xs, int N){
  int id = blockIdx.x*blockDim.x + threadIdx.x;
  if (id >= N*16) return;
  int row = id >> 4;
  float d = dinv[row];
  float4 v = x[id];
  ushort4 o;
  o.x = f2bf(v.x*d); o.y = f2bf(v.y*d); o.z = f2bf(v.z*d); o.w = f2bf(v.w*d);
  xs[id] = o;
}

// hs = bf16((bf16(h1)*sc1 + sh1) * dinv[node]) : N x 128
__global__ void k_prep2(const uint2* __restrict__ h1, const float* __restrict__ dinv,
                        const float4* __restrict__ sc, const float4* __restrict__ sh,
                        ushort4* __restrict__ hs, int N){
  int id = blockIdx.x*blockDim.x + threadIdx.x;
  if (id >= N*32) return;
  int row = id >> 5, lane = id & 31;
  float d = dinv[row];
  uint2 w = h1[id];
  float f0,f1,f2,f3;
  bf2f2(w.x, f0, f1); bf2f2(w.y, f2, f3);
  float4 s4 = sc[lane], h4 = sh[lane];
  ushort4 o;
  o.x = f2bf(fmaf(f0, s4.x, h4.x)*d);
  o.y = f2bf(fmaf(f1, s4.y, h4.y)*d);
  o.z = f2bf(fmaf(f2, s4.z, h4.z)*d);
  o.w = f2bf(fmaf(f3, s4.w, h4.w)*d);
  hs[id] = o;
}

// emb[g,:] = (cnt>0) ? mean * scale2 + shift2 : 0
__global__ void k_emb(const float* __restrict__ embsum, const int* __restrict__ cnt,
                      const float* __restrict__ sc, const float* __restrict__ sh,
                      float* __restrict__ emb, int G){
  int id = blockIdx.x*blockDim.x + threadIdx.x;
  if (id >= G*64) return;
  int g = id >> 6, l = id & 63;
  float4 s = ((const float4*)embsum)[id];
  int c = cnt[g];
  float4 o = {0.f,0.f,0.f,0.f};
  if (c > 0){
    float inv = 1.0f / (float)c;
    int k = l*4;
    o.x = fmaf(s.x*inv, sc[k+0], sh[k+0]);
    o.y = fmaf(s.y*inv, sc[k+1], sh[k+1]);
    o.z = fmaf(s.z*inv, sc[k+2], sh[k+2]);
    o.w = fmaf(s.w*inv, sc[k+3], sh[k+3]);
  }
  ((float4*)emb)[id] = o;
}

// ---------------- aggregation (gather) kernels, bf16 in / bf16 out ----------------
// agg1: z1[c,:] = bf16(dinv[c] * (sum xs[r,:] + xs[c,:])), F=64, 8 lanes/node
__global__ __launch_bounds__(256) void k_agg1(
    const uint4* __restrict__ xs, const int* __restrict__ offs, const int* __restrict__ csr,
    const float* __restrict__ dinv, uint4* __restrict__ z, int N)
{
  int sub = threadIdx.x >> 3, lane = threadIdx.x & 7;
  int node = blockIdx.x*32 + sub;
  if (node >= N) return;
  int s = offs[node], e = offs[node+1];
  float acc[8] = {};
  auto add8 = [&](uint4 v){
    float f0,f1,f2,f3,f4,f5,f6,f7;
    bf2f2(v.x, f0, f1); bf2f2(v.y, f2, f3);
    bf2f2(v.z, f4, f5); bf2f2(v.w, f6, f7);
    acc[0]+=f0; acc[1]+=f1; acc[2]+=f2; acc[3]+=f3;
    acc[4]+=f4; acc[5]+=f5; acc[6]+=f6; acc[7]+=f7;
  };
  int i = s;
  for (; i + 2 <= e; i += 2){
    int r0 = csr[i], r1 = csr[i+1];
    uint4 v0 = xs[r0*8 + lane];
    uint4 v1 = xs[r1*8 + lane];
    add8(v0); add8(v1);
  }
  if (i < e) add8(xs[csr[i]*8 + lane]);
  add8(xs[node*8 + lane]);
  float d = dinv[node];
  uint4 o;
  o.x = pack2bf(acc[0]*d, acc[1]*d);
  o.y = pack2bf(acc[2]*d, acc[3]*d);
  o.z = pack2bf(acc[4]*d, acc[5]*d);
  o.w = pack2bf(acc[6]*d, acc[7]*d);
  z[node*8 + lane] = o;
}

// agg2: z2[c,:] = bf16(dinv[c] * (sum hs[r,:] + hs[c,:])), F=128, 16 lanes/node
__global__ __launch_bounds__(256) void k_agg2(
    const uint4* __restrict__ hs, const int* __restrict__ offs, const int* __restrict__ csr,
    const float* __restrict__ dinv, uint4* __restrict__ z, int N)
{
  int sub = threadIdx.x >> 4, lane = threadIdx.x & 15;
  int node = blockIdx.x*16 + sub;
  if (node >= N) return;
  int s = offs[node], e = offs[node+1];
  float acc[8] = {};
  auto add8 = [&](uint4 v){
    float f0,f1,f2,f3,f4,f5,f6,f7;
    bf2f2(v.x, f0, f1); bf2f2(v.y, f2, f3);
    bf2f2(v.z, f4, f5); bf2f2(v.w, f6, f7);
    acc[0]+=f0; acc[1]+=f1; acc[2]+=f2; acc[3]+=f3;
    acc[4]+=f4; acc[5]+=f5; acc[6]+=f6; acc[7]+=f7;
  };
  int i = s;
  for (; i + 2 <= e; i += 2){
    int r0 = csr[i], r1 = csr[i+1];
    uint4 v0 = hs[r0*16 + lane];
    uint4 v1 = hs[r1*16 + lane];
    add8(v0); add8(v1);
  }
  if (i < e) add8(hs[csr[i]*16 + lane]);
  add8(hs[node*16 + lane]);
  float d = dinv[node];
  uint4 o;
  o.x = pack2bf(acc[0]*d, acc[1]*d);
  o.y = pack2bf(acc[2]*d, acc[3]*d);
  o.z = pack2bf(acc[4]*d, acc[5]*d);
  o.w = pack2bf(acc[6]*d, acc[7]*d);
  z[node*16 + lane] = o;
}

// ---------------- GEMM: out = relu(A @ W + bias), + bn stats ----------------
template<int K, int NWTOT, bool CONCAT, bool AFFINE, bool BF16A, bool BF16OUT>
__global__ __launch_bounds__(256) void k_gemm_mlp(
    const void* __restrict__ A0v, const float* __restrict__ A1,
    const float* __restrict__ W,
    const float* __restrict__ scale, const float* __restrict__ shift,
    const float* __restrict__ bias,
    void* __restrict__ outv, float* __restrict__ gstats, int nrows)
{
  __shared__ float As[32*68];
  __shared__ float Bs[32*128];
  __shared__ float s_sum[128], s_sq[128];
  int m0 = blockIdx.x*64;
  int n0 = blockIdx.y*128;
  int tid  = threadIdx.x;
  int tcol = tid & 31, trow = tid >> 5;
  float acc[8][4] = {};
  constexpr int NCH = (K + 31) / 32;
  for (int ch = 0; ch < NCH; ch++){
    int kc0 = ch*32;
    #pragma unroll
    for (int j = 0; j < 2; j++){
      int fid = tid + j*256;
      int rr = fid >> 3; int k4 = (fid & 7) << 2;
      int row = m0 + rr;
      int kg = kc0 + k4;
      float4 v = {0.f,0.f,0.f,0.f};
      if (row < nrows){
        if constexpr (BF16A){
          const uint16_t* Ab = (const uint16_t*)A0v;
          uint2 w = *(const uint2*)(Ab + (size_t)row*K + kg);
          bf2f2(w.x, v.x, v.y); bf2f2(w.y, v.z, v.w);
        } else if constexpr (CONCAT){
          const float* A0 = (const float*)A0v;
          if (kg < 256)      v = *(const float4*)(A0 + (size_t)row*256 + kg);
          else if (kg < 456) v = *(const float4*)(A1 + (size_t)row*200 + (kg-256));
        } else {
          const float* A0 = (const float*)A0v;
          v = *(const float4*)(A0 + (size_t)row*K + kg);
        }
      }
      if constexpr (AFFINE){
        float4 scv = *(const float4*)(scale + kg);
        float4 shv = *(const float4*)(shift + kg);
        v.x = fmaf(v.x, scv.x, shv.x);
        v.y = fmaf(v.y, scv.y, shv.y);
        v.z = fmaf(v.z, scv.z, shv.z);
        v.w = fmaf(v.w, scv.w, shv.w);
      }
      As[(k4+0)*68 + rr] = v.x;
      As[(k4+1)*68 + rr] = v.y;
      As[(k4+2)*68 + rr] = v.z;
      As[(k4+3)*68 + rr] = v.w;
    }
    #pragma unroll
    for (int j = 0; j < 4; j++){
      int fid = tid + j*256;
      int kk = fid >> 5; int c4 = (fid & 31) << 2;
      int kg = kc0 + kk;
      float4 v = {0.f,0.f,0.f,0.f};
      if (kg < K) v = *(const float4*)(W + (size_t)kg*NWTOT + n0 + c4);
      *(float4*)(Bs + kk*128 + c4) = v;
    }
    __syncthreads();
    #pragma unroll
    for (int kk = 0; kk < 32; kk++){
      float4 b  = *(const float4*)(Bs + kk*128 + tcol*4);
      float4 a0 = *(const float4*)(As + kk*68 + trow*8);
      float4 a1 = *(const float4*)(As + kk*68 + trow*8 + 4);
      float a[8] = {a0.x,a0.y,a0.z,a0.w,a1.x,a1.y,a1.z,a1.w};
      #pragma unroll
      for (int r = 0; r < 8; r++){
        acc[r][0] = fmaf(a[r], b.x, acc[r][0]);
        acc[r][1] = fmaf(a[r], b.y, acc[r][1]);
        acc[r][2] = fmaf(a[r], b.z, acc[r][2]);
        acc[r][3] = fmaf(a[r], b.w, acc[r][3]);
      }
    }
    __syncthreads();
  }
  for (int i = tid; i < 128; i += 256){ s_sum[i] = 0.f; s_sq[i] = 0.f; }
  __syncthreads();
  float4 bv = *(const float4*)(bias + n0 + tcol*4);
  float psum[4] = {0,0,0,0}, psq[4] = {0,0,0,0};
  #pragma unroll
  for (int r = 0; r < 8; r++){
    int row = m0 + trow*8 + r;
    if (row < nrows){
      float4 o;
      o.x = fmaxf(acc[r][0] + bv.x, 0.f);
      o.y = fmaxf(acc[r][1] + bv.y, 0.f);
      o.z = fmaxf(acc[r][2] + bv.z, 0.f);
      o.w = fmaxf(acc[r][3] + bv.w, 0.f);
      if constexpr (BF16OUT){
        uint16_t* op = (uint16_t*)outv;
        uint2 w; w.x = pack2bf(o.x, o.y); w.y = pack2bf(o.z, o.w);
        *(uint2*)(op + (size_t)row*NWTOT + n0 + tcol*4) = w;
      } else {
        float* op = (float*)outv;
        *(float4*)(op + (size_t)row*NWTOT + n0 + tcol*4) = o;
      }
      psum[0] += o.x; psq[0] += o.x*o.x;
      psum[1] += o.y; psq[1] += o.y*o.y;
      psum[2] += o.z; psq[2] += o.z*o.z;
      psum[3] += o.w; psq[3] += o.w*o.w;
    }
  }
  int f0 = tcol*4;
  atomicAdd(&s_sum[f0+0], psum[0]); atomicAdd(&s_sq[f0+0], psq[0]);
  atomicAdd(&s_sum[f0+1], psum[1]); atomicAdd(&s_sq[f0+1], psq[1]);
  atomicAdd(&s_sum[f0+2], psum[2]); atomicAdd(&s_sq[f0+2], psq[2]);
  atomicAdd(&s_sum[f0+3], psum[3]); atomicAdd(&s_sq[f0+3], psq[3]);
  __syncthreads();
  float* gs = gstats + (size_t)(blockIdx.x & 31)*(2*NWTOT);
  for (int i = tid; i < 128; i += 256){
    atomicAdd(&gs[n0 + i], s_sum[i]);
    atomicAdd(&gs[NWTOT + n0 + i], s_sq[i]);
  }
}

// ---------------- GEMM + fused relu/pool/stats (h2 never materialized) ----------------
template<int K, int NWTOT>
__global__ __launch_bounds__(256) void k_gemm_pool(
    const uint16_t* __restrict__ A, const float* __restrict__ W,
    const float* __restrict__ bias, const int* __restrict__ batch,
    float* __restrict__ embsum, float* __restrict__ gstats, int nrows)
{
  __shared__ float As[32*68];
  __shared__ float Bs[32*128];
  __shared__ float s_sum[128], s_sq[128];
  __shared__ int s_batch[64];
  int m0 = blockIdx.x*64;
  int n0 = blockIdx.y*128;
  int tid  = threadIdx.x;
  int tcol = tid & 31, trow = tid >> 5;
  float acc[8][4] = {};
  constexpr int NCH = (K + 31) / 32;
  for (int ch = 0; ch < NCH; ch++){
    int kc0 = ch*32;
    #pragma unroll
    for (int j = 0; j < 2; j++){
      int fid = tid + j*256;
      int rr = fid >> 3; int k4 = (fid & 7) << 2;
      int row = m0 + rr;
      int kg = kc0 + k4;
      float4 v = {0.f,0.f,0.f,0.f};
      if (row < nrows){
        uint2 w = *(const uint2*)(A + (size_t)row*K + kg);
        bf2f2(w.x, v.x, v.y); bf2f2(w.y, v.z, v.w);
      }
      As[(k4+0)*68 + rr] = v.x;
      As[(k4+1)*68 + rr] = v.y;
      As[(k4+2)*68 + rr] = v.z;
      As[(k4+3)*68 + rr] = v.w;
    }
    #pragma unroll
    for (int j = 0; j < 4; j++){
      int fid = tid + j*256;
      int kk = fid >> 5; int c4 = (fid & 31) << 2;
      int kg = kc0 + kk;
      float4 v = *(const float4*)(W + (size_t)kg*NWTOT + n0 + c4);
      *(float4*)(Bs + kk*128 + c4) = v;
    }
    __syncthreads();
    #pragma unroll
    for (int kk = 0; kk < 32; kk++){
      float4 b  = *(const float4*)(Bs + kk*128 + tcol*4);
      float4 a0 = *(const float4*)(As + kk*68 + trow*8);
      float4 a1 = *(const float4*)(As + kk*68 + trow*8 + 4);
      float a[8] = {a0.x,a0.y,a0.z,a0.w,a1.x,a1.y,a1.z,a1.w};
      #pragma unroll
      for (int r = 0; r < 8; r++){
        acc[r][0] = fmaf(a[r], b.x, acc[r][0]);
        acc[r][1] = fmaf(a[r], b.y, acc[r][1]);
        acc[r][2] = fmaf(a[r], b.z, acc[r][2]);
        acc[r][3] = fmaf(a[r], b.w, acc[r][3]);
      }
    }
    __syncthreads();
  }
  if (tid < 64) s_batch[tid] = (m0 + tid < nrows) ? batch[m0 + tid] : -1;
  for (int i = tid; i < 128; i += 256){ s_sum[i] = 0.f; s_sq[i] = 0.f; }
  __syncthreads();
  float4 bv = *(const float4*)(bias + n0 + tcol*4);
  float psum[4] = {0,0,0,0}, psq[4] = {0,0,0,0};
  float run[4] = {0,0,0,0};
  int runb = -1;
  #pragma unroll
  for (int r = 0; r < 8; r++){
    int row = m0 + trow*8 + r;
    if (row < nrows){
      float ox = fmaxf(acc[r][0] + bv.x, 0.f);
      float oy = fmaxf(acc[r][1] + bv.y, 0.f);
      float oz = fmaxf(acc[r][2] + bv.z, 0.f);
      float ow = fmaxf(acc[r][3] + bv.w, 0.f);
      psum[0] += ox; psq[0] += ox*ox;
      psum[1] += oy; psq[1] += oy*oy;
      psum[2] += oz; psq[2] += oz*oz;
      psum[3] += ow; psq[3] += ow*ow;
      int b = s_batch[trow*8 + r];
      if (b != runb){
        if (runb >= 0){
          float* es = embsum + (size_t)runb*NWTOT + n0 + tcol*4;
          atomicAdd(es+0, run[0]); atomicAdd(es+1, run[1]);
          atomicAdd(es+2, run[2]); atomicAdd(es+3, run[3]);
        }
        runb = b;
        run[0] = ox; run[1] = oy; run[2] = oz; run[3] = ow;
      } else {
        run[0] += ox; run[1] += oy; run[2] += oz; run[3] += ow;
      }
    }
  }
  if (runb >= 0){
    float* es = embsum + (size_t)runb*NWTOT + n0 + tcol*4;
    atomicAdd(es+0, run[0]); atomicAdd(es+1, run[1]);
    atomicAdd(es+2, run[2]); atomicAdd(es+3, run[3]);
  }
  int f0 = tcol*4;
  atomicAdd(&s_sum[f0+0], psum[0]); atomicAdd(&s_sq[f0+0], psq[0]);
  atomicAdd(&s_sum[f0+1], psum[1]); atomicAdd(&s_sq[f0+1], psq[1]);
  atomicAdd(&s_sum[f0+2], psum[2]); atomicAdd(&s_sq[f0+2], psq[2]);
  atomicAdd(&s_sum[f0+3], psum[3]); atomicAdd(&s_sq[f0+3], psq[3]);
  __syncthreads();
  float* gs = gstats + (size_t)(blockIdx.x & 31)*(2*NWTOT);
  for (int i = tid; i < 128; i += 256){
    atomicAdd(&gs[n0 + i], s_sum[i]);
    atomicAdd(&gs[NWTOT + n0 + i], s_sq[i]);
  }
}

// ---------------- final: out[g] = bn4(a2[g,:]) . mW3 + mb3 ----------------
__global__ __launch_bounds__(256) void k_final(
    const float* __restrict__ a2, const float* __restrict__ sc, const float* __restrict__ sh,
    const float* __restrict__ w, const float* __restrict__ b, float* __restrict__ out, int G)
{
  int gid  = blockIdx.x*blockDim.x + threadIdx.x;
  int wid  = gid >> 6;
  int lane = gid & 63;
  if (wid >= G) return;
  float2 v = ((const float2*)(a2 + (size_t)wid*128))[lane];
  int k = lane*2;
  float s = fmaf(v.x, sc[k], sh[k]) * w[k] + fmaf(v.y, sc[k+1], sh[k+1]) * w[k+1];
  #pragma unroll
  for (int o = 32; o > 0; o >>= 1) s += __shfl_down(s, o, 64);
  if (lane == 0) out[wid] = s + b[0];
}

// ---------------- launcher ----------------
extern "C" void kernel_launch(void* const* d_in, const int* in_sizes, int n_in,
                              void* d_out, int out_size, void* d_ws, size_t ws_size,
                              hipStream_t stream)
{
  (void)n_in; (void)out_size; (void)ws_size;
  const float* x    = (const float*)d_in[0];
  const int*   ei   = (const int*)d_in[1];
  const int*   batch= (const int*)d_in[2];
  const float* rdk  = (const float*)d_in[3];
  const float* W1   = (const float*)d_in[4];
  const float* b1   = (const float*)d_in[5];
  const float* g1   = (const float*)d_in[6];
  const float* be1  = (const float*)d_in[7];
  const float* W2   = (const float*)d_in[8];
  const float* b2   = (const float*)d_in[9];
  const float* g2   = (const float*)d_in[10];
  const float* be2  = (const float*)d_in[11];
  const float* mW1  = (const float*)d_in[12];
  const float* mb1  = (const float*)d_in[13];
  const float* mg1  = (const float*)d_in[14];
  const float* mbe1 = (const float*)d_in[15];
  const float* mW2  = (const float*)d_in[16];
  const float* mb2  = (const float*)d_in[17];
  const float* mg2  = (const float*)d_in[18];
  const float* mbe2 = (const float*)d_in[19];
  const float* mW3  = (const float*)d_in[20];
  const float* mb3  = (const float*)d_in[21];

  const int N = in_sizes[0] / 64;
  const int E = in_sizes[1] / 2;
  const int G = in_sizes[3] / 200;
  const int* erow = ei;
  const int* ecol = ei + E;
  const int nb = (N + 63) >> 6;

  size_t off = 0;
  auto alloc = [&](size_t bytes)->char*{
    char* p = (char*)d_ws + off;
    off += (bytes + 255) & ~(size_t)255;
    return p;
  };
  int*   indeg  = (int*)  alloc((size_t)N*4);
  int*   offs   = (int*)  alloc(((size_t)N+1)*4);
  int*   csr    = (int*)  alloc((size_t)E*4);
  uint2* ebuf   = (uint2*)alloc((size_t)E*8);
  int*   bcur   = (int*)  alloc((size_t)nb*4);
  float* dinv   = (float*)alloc((size_t)N*4);
  int*   bsum   = (int*)  alloc(1024*4);
  uint16_t* xs  = (uint16_t*)alloc((size_t)N*64*2);
  uint16_t* z1  = (uint16_t*)alloc((size_t)N*64*2);
  uint16_t* h1  = (uint16_t*)alloc((size_t)N*128*2);
  uint16_t* hs  = (uint16_t*)alloc((size_t)N*128*2);
  uint16_t* z2  = (uint16_t*)alloc((size_t)N*128*2);
  float* embsum = (float*)alloc((size_t)G*256*4);
  int*   cnt    = (int*)  alloc((size_t)G*4);
  float* emb    = (float*)alloc((size_t)G*256*4);
  float* a1     = (float*)alloc((size_t)G*256*4);
  float* a2     = (float*)alloc((size_t)G*128*4);
  float* gstats = (float*)alloc((size_t)4*32*2*256*4);
  float* scsh   = (float*)alloc((size_t)4*2*256*4);

  float* gs0 = gstats;
  float* gs1 = gstats + 32*2*256;
  float* gs2 = gstats + 2*32*2*256;
  float* gs3 = gstats + 3*32*2*256;
  float* sc1 = scsh;        float* sh1 = scsh + 256;
  float* sc2 = scsh + 512;  float* sh2 = scsh + 768;
  float* sc3 = scsh + 1024; float* sh3 = scsh + 1280;
  float* sc4 = scsh + 1536; float* sh4 = scsh + 1792;

  hipMemsetAsync(indeg,  0, (size_t)N*4, stream);
  hipMemsetAsync(gstats, 0, (size_t)4*32*2*256*4, stream);
  hipMemsetAsync(embsum, 0, (size_t)G*256*4, stream);
  hipMemsetAsync(cnt,    0, (size_t)G*4, stream);

  int nblkE = (E + 255) / 256;
  int nblkN = (N + 255) / 256;
  int nscan = (N + 1023) / 1024;
  int mblk  = (N + 63) / 64;
  int gblk  = (G + 63) / 64;

  // CSR build: count -> scan -> 2-pass bucket sort
  k_count<<<nblkE,256,0,stream>>>(ecol, indeg, E);
  k_scan1<<<nscan,256,0,stream>>>(indeg, offs, bsum, N);
  k_scan2<<<1,128,0,stream>>>(bsum, nscan);
  k_scan3<<<nblkN,256,0,stream>>>(offs, bsum, N, E);
  k_dinv<<<nblkN,256,0,stream>>>(indeg, dinv, N);
  k_initbcur<<<(nb+255)/256,256,0,stream>>>(offs, bcur, N, nb);
  k_passA<<<nblkE,256,0,stream>>>(erow, ecol, bcur, ebuf, E);
  k_passB<<<nb,256,0,stream>>>(ebuf, offs, csr, N);
  k_cnt<<<nblkN,256,0,stream>>>(batch, cnt, N);

  // layer 1: aggregate-first (F=64), then GEMM 64->128 with fused relu+stats
  k_prep1<<<(N*16+255)/256,256,0,stream>>>((const float4*)x, dinv, (ushort4*)xs, N);
  k_agg1<<<(N+31)/32,256,0,stream>>>((const uint4*)xs, offs, csr, dinv, (uint4*)z1, N);
  k_gemm_mlp<64,128,false,false,true,true><<<dim3(mblk,1),256,0,stream>>>(z1, nullptr, W1, nullptr, nullptr, b1, h1, gs0, N);
  k_bnfin<<<1,256,0,stream>>>(gs0, 128, 1.0f/(float)N, g1, be1, sc1, sh1);

  // layer 2: fold bn1 affine + dinv into bf16 payload, aggregate (F=128), GEMM 128->256 + fused pool
  k_prep2<<<(N*32+255)/256,256,0,stream>>>((const uint2*)h1, dinv, (const float4*)sc1, (const float4*)sh1, (ushort4*)hs, N);
  k_agg2<<<(N+15)/16,256,0,stream>>>((const uint4*)hs, offs, csr, dinv, (uint4*)z2, N);
  k_gemm_pool<128,256><<<dim3(mblk,2),256,0,stream>>>(z2, W2, b2, batch, embsum, gs1, N);
  k_bnfin<<<1,256,0,stream>>>(gs1, 256, 1.0f/(float)N, g2, be2, sc2, sh2);

  // graph head
  k_emb<<<(G*64+255)/256,256,0,stream>>>(embsum, cnt, sc2, sh2, emb, G);
  k_gemm_mlp<456,256,true,false,false,false><<<dim3(gblk,2),256,0,stream>>>(emb, rdk, mW1, nullptr, nullptr, mb1, a1, gs2, G);
  k_bnfin<<<1,256,0,stream>>>(gs2, 256, 1.0f/(float)G, mg1, mbe1, sc3, sh3);
  k_gemm_mlp<256,128,false,true,false,false><<<dim3(gblk,1),256,0,stream>>>(a1, nullptr, mW2, sc3, sh3, mb2, a2, gs3, G);
  k_bnfin<<<1,256,0,stream>>>(gs3, 128, 1.0f/(float)G, mg2, mbe2, sc4, sh4);
  k_final<<<(G+3)/4,256,0,stream>>>(a2, sc4, sh4, mW3, mb3, (float*)d_out, G);
}

// Round 4
// 811.953 us; speedup vs baseline: 1.5213x; 1.5213x over previous
//
#include <hip/hip_runtime.h>
#include <cstdint>
#include <cstddef>

#define BN_EPS 1e-5f

// ---------------- helpers ----------------

__device__ inline uint16_t f2bf(float f){
  union {float f; uint32_t u;} v; v.f = f;
  uint32_t u = v.u;
  return (uint16_t)((u + 0x7FFFu + ((u >> 16) & 1u)) >> 16);
}

__device__ inline uint32_t pack2bf(float a, float b){
  return (uint32_t)f2bf(a) | ((uint32_t)f2bf(b) << 16);
}

__device__ inline void bf2f2(uint32_t w, float& a, float& b){
  union {uint32_t u; float f;} ua, ub;
  ua.u = w << 16; ub.u = w & 0xFFFF0000u;
  a = ua.f; b = ub.f;
}

// ---------------- graph preprocessing ----------------

__global__ void k_count(const int* __restrict__ col, int* __restrict__ indeg, int E){
  int e = blockIdx.x*blockDim.x + threadIdx.x;
  if (e < E) atomicAdd(&indeg[col[e]], 1);
}

// exclusive scan, 1024 elems/block
__global__ void k_scan1(const int* __restrict__ in, int* __restrict__ out, int* __restrict__ bsum, int n){
  __shared__ int s[256];
  int t = threadIdx.x;
  int base = blockIdx.x*1024 + t*4;
  int v0 = (base+0 < n) ? in[base+0] : 0;
  int v1 = (base+1 < n) ? in[base+1] : 0;
  int v2 = (base+2 < n) ? in[base+2] : 0;
  int v3 = (base+3 < n) ? in[base+3] : 0;
  int lsum = v0+v1+v2+v3;
  s[t] = lsum;
  __syncthreads();
  for (int off=1; off<256; off<<=1){
    int x = 0;
    if (t >= off) x = s[t-off];
    __syncthreads();
    if (t >= off) s[t] += x;
    __syncthreads();
  }
  int excl = s[t] - lsum;
  if (base+0 < n) out[base+0] = excl;
  if (base+1 < n) out[base+1] = excl + v0;
  if (base+2 < n) out[base+2] = excl + v0 + v1;
  if (base+3 < n) out[base+3] = excl + v0 + v1 + v2;
  if (t == 255) bsum[blockIdx.x] = s[255];
}

// exclusive scan of block sums (nblk <= 128)
__global__ void k_scan2(int* bsum, int nblk){
  __shared__ int s[128];
  int t = threadIdx.x;
  int v = (t < nblk) ? bsum[t] : 0;
  s[t] = v;
  __syncthreads();
  for (int off=1; off<128; off<<=1){
    int x = 0;
    if (t >= off) x = s[t-off];
    __syncthreads();
    if (t >= off) s[t] += x;
    __syncthreads();
  }
  if (t < nblk) bsum[t] = s[t] - v;
}

__global__ void k_scan3(int* __restrict__ out, const int* __restrict__ bsum, int n, int E){
  int i = blockIdx.x*blockDim.x + threadIdx.x;
  if (i < n) out[i] += bsum[i>>10];
  if (i == 0) out[n] = E;
}

__global__ void k_dinv(const int* __restrict__ indeg, float* __restrict__ dinv, int n){
  int i = blockIdx.x*blockDim.x + threadIdx.x;
  if (i < n) dinv[i] = 1.0f / sqrtf((float)(indeg[i] + 1));
}

// bucket = col >> 9 (512 nodes per bucket); gcur[b] = ebuf start of bucket b
__global__ void k_initbcur(const int* __restrict__ offs, int* __restrict__ bcur, int N){
  int b = blockIdx.x*blockDim.x + threadIdx.x;
  if (b < 256) bcur[b] = offs[min(b<<9, N)];
}

// pass A: block-private histogram partition of edges into 512-node buckets.
// Tile of 4096 edges per block; one global atomic per (block,bucket).
#define PA_TILE 4096
__global__ __launch_bounds__(256) void k_passA(
    const int* __restrict__ row, const int* __restrict__ col,
    int* __restrict__ gcur, uint2* __restrict__ ebuf, int E)
{
  __shared__ int hist[256];
  __shared__ int rbase[256];
  int t = threadIdx.x;
  int start = blockIdx.x * PA_TILE;
  for (int i = t; i < 256; i += 256) hist[i] = 0;
  __syncthreads();
  int myr[16], myc[16], myb[16];
  #pragma unroll
  for (int j = 0; j < 16; j++){
    int e = start + t + j*256;
    if (e < E){
      int r = row[e], c = col[e];
      myr[j] = r; myc[j] = c; myb[j] = c >> 9;
      atomicAdd(&hist[myb[j]], 1);
    } else myb[j] = -1;
  }
  __syncthreads();
  for (int i = t; i < 256; i += 256){
    int h = hist[i];
    rbase[i] = (h > 0) ? atomicAdd(&gcur[i], h) : 0;
  }
  __syncthreads();
  for (int i = t; i < 256; i += 256) hist[i] = 0;
  __syncthreads();
  #pragma unroll
  for (int j = 0; j < 16; j++){
    if (myb[j] >= 0){
      int pos = rbase[myb[j]] + atomicAdd(&hist[myb[j]], 1);
      uint2 rc; rc.x = (unsigned)myr[j]; rc.y = (unsigned)myc[j];
      ebuf[pos] = rc;
    }
  }
}

// pass B: per-bucket CSR fill, 512 LDS cursors, L2-local writes
__global__ __launch_bounds__(256) void k_passB(const uint2* __restrict__ ebuf,
                                               const int* __restrict__ offs,
                                               int* __restrict__ csr, int N){
  __shared__ int cur[512];
  int b = blockIdx.x;
  int base = b << 9;
  int t = threadIdx.x;
  for (int i = t; i < 512; i += 256) cur[i] = offs[min(base + i, N)];
  int s = offs[min(base, N)];
  int e = offs[min(base + 512, N)];
  __syncthreads();
  for (int i = s + t; i < e; i += 256){
    uint2 rc = ebuf[i];
    int local = (int)rc.y - base;
    int pos = atomicAdd(&cur[local], 1);
    csr[pos] = (int)rc.x;
  }
}

__global__ void k_cnt(const int* __restrict__ batch, int* __restrict__ cnt, int n){
  int i = blockIdx.x*blockDim.x + threadIdx.x;
  if (i < n) atomicAdd(&cnt[batch[i]], 1);
}

// per-column bn finalize: scale = g*rstd, shift = be - mu*scale
__global__ void k_bnfin(const float* __restrict__ region, int F, float invCount,
                        const float* __restrict__ g, const float* __restrict__ be,
                        float* __restrict__ scale, float* __restrict__ shift){
  int i = blockIdx.x*blockDim.x + threadIdx.x;
  if (i >= F) return;
  float s = 0.f, q = 0.f;
  for (int sl = 0; sl < 32; sl++){
    s += region[sl*2*F + i];
    q += region[sl*2*F + F + i];
  }
  float mu  = s * invCount;
  float var = q * invCount - mu*mu;
  if (var < 0.f) var = 0.f;
  float rstd = 1.0f / sqrtf(var + BN_EPS);
  float sc = g[i] * rstd;
  scale[i] = sc;
  shift[i] = be[i] - mu * sc;
}

// xs = bf16(x * dinv[node]) : N x 64
__global__ void k_prep1(const float4* __restrict__ x, const float* __restrict__ dinv,
                        ushort4* __restrict__ xs, int N){
  int id = blockIdx.x*blockDim.x + threadIdx.x;
  if (id >= N*16) return;
  int row = id >> 4;
  float d = dinv[row];
  float4 v = x[id];
  ushort4 o;
  o.x = f2bf(v.x*d); o.y = f2bf(v.y*d); o.z = f2bf(v.z*d); o.w = f2bf(v.w*d);
  xs[id] = o;
}

// hs = bf16((bf16(h1)*sc1 + sh1) * dinv[node]) : N x 128
__global__ void k_prep2(const uint2* __restrict__ h1, const float* __restrict__ dinv,
                        const float4* __restrict__ sc, const float4* __restrict__ sh,
                        ushort4* __restrict__ hs, int N){
  int id = blockIdx.x*blockDim.x + threadIdx.x;
  if (id >= N*32) return;
  int row = id >> 5, lane = id & 31;
  float d = dinv[row];
  uint2 w = h1[id];
  float f0,f1,f2,f3;
  bf2f2(w.x, f0, f1); bf2f2(w.y, f2, f3);
  float4 s4 = sc[lane], h4 = sh[lane];
  ushort4 o;
  o.x = f2bf(fmaf(f0, s4.x, h4.x)*d);
  o.y = f2bf(fmaf(f1, s4.y, h4.y)*d);
  o.z = f2bf(fmaf(f2, s4.z, h4.z)*d);
  o.w = f2bf(fmaf(f3, s4.w, h4.w)*d);
  hs[id] = o;
}

// emb[g,:] = (cnt>0) ? mean * scale2 + shift2 : 0
__global__ void k_emb(const float* __restrict__ embsum, const int* __restrict__ cnt,
                      const float* __restrict__ sc, const float* __restrict__ sh,
                      float* __restrict__ emb, int G){
  int id = blockIdx.x*blockDim.x + threadIdx.x;
  if (id >= G*64) return;
  int g = id >> 6, l = id & 63;
  float4 s = ((const float4*)embsum)[id];
  int c = cnt[g];
  float4 o = {0.f,0.f,0.f,0.f};
  if (c > 0){
    float inv = 1.0f / (float)c;
    int k = l*4;
    o.x = fmaf(s.x*inv, sc[k+0], sh[k+0]);
    o.y = fmaf(s.y*inv, sc[k+1], sh[k+1]);
    o.z = fmaf(s.z*inv, sc[k+2], sh[k+2]);
    o.w = fmaf(s.w*inv, sc[k+3], sh[k+3]);
  }
  ((float4*)emb)[id] = o;
}

// ---------------- aggregation (gather) kernels, bf16 in / bf16 out ----------------
// agg1: z1[c,:] = bf16(dinv[c] * (sum xs[r,:] + xs[c,:])), F=64, 8 lanes/node
__global__ __launch_bounds__(256) void k_agg1(
    const uint4* __restrict__ xs, const int* __restrict__ offs, const int* __restrict__ csr,
    const float* __restrict__ dinv, uint4* __restrict__ z, int N)
{
  int sub = threadIdx.x >> 3, lane = threadIdx.x & 7;
  int node = blockIdx.x*32 + sub;
  if (node >= N) return;
  int s = offs[node], e = offs[node+1];
  float acc[8] = {};
  auto add8 = [&](uint4 v){
    float f0,f1,f2,f3,f4,f5,f6,f7;
    bf2f2(v.x, f0, f1); bf2f2(v.y, f2, f3);
    bf2f2(v.z, f4, f5); bf2f2(v.w, f6, f7);
    acc[0]+=f0; acc[1]+=f1; acc[2]+=f2; acc[3]+=f3;
    acc[4]+=f4; acc[5]+=f5; acc[6]+=f6; acc[7]+=f7;
  };
  int i = s;
  for (; i + 2 <= e; i += 2){
    int r0 = csr[i], r1 = csr[i+1];
    uint4 v0 = xs[r0*8 + lane];
    uint4 v1 = xs[r1*8 + lane];
    add8(v0); add8(v1);
  }
  if (i < e) add8(xs[csr[i]*8 + lane]);
  add8(xs[node*8 + lane]);
  float d = dinv[node];
  uint4 o;
  o.x = pack2bf(acc[0]*d, acc[1]*d);
  o.y = pack2bf(acc[2]*d, acc[3]*d);
  o.z = pack2bf(acc[4]*d, acc[5]*d);
  o.w = pack2bf(acc[6]*d, acc[7]*d);
  z[node*8 + lane] = o;
}

// agg2: z2[c,:] = bf16(dinv[c] * (sum hs[r,:] + hs[c,:])), F=128, 16 lanes/node
__global__ __launch_bounds__(256) void k_agg2(
    const uint4* __restrict__ hs, const int* __restrict__ offs, const int* __restrict__ csr,
    const float* __restrict__ dinv, uint4* __restrict__ z, int N)
{
  int sub = threadIdx.x >> 4, lane = threadIdx.x & 15;
  int node = blockIdx.x*16 + sub;
  if (node >= N) return;
  int s = offs[node], e = offs[node+1];
  float acc[8] = {};
  auto add8 = [&](uint4 v){
    float f0,f1,f2,f3,f4,f5,f6,f7;
    bf2f2(v.x, f0, f1); bf2f2(v.y, f2, f3);
    bf2f2(v.z, f4, f5); bf2f2(v.w, f6, f7);
    acc[0]+=f0; acc[1]+=f1; acc[2]+=f2; acc[3]+=f3;
    acc[4]+=f4; acc[5]+=f5; acc[6]+=f6; acc[7]+=f7;
  };
  int i = s;
  for (; i + 2 <= e; i += 2){
    int r0 = csr[i], r1 = csr[i+1];
    uint4 v0 = hs[r0*16 + lane];
    uint4 v1 = hs[r1*16 + lane];
    add8(v0); add8(v1);
  }
  if (i < e) add8(hs[csr[i]*16 + lane]);
  add8(hs[node*16 + lane]);
  float d = dinv[node];
  uint4 o;
  o.x = pack2bf(acc[0]*d, acc[1]*d);
  o.y = pack2bf(acc[2]*d, acc[3]*d);
  o.z = pack2bf(acc[4]*d, acc[5]*d);
  o.w = pack2bf(acc[6]*d, acc[7]*d);
  z[node*16 + lane] = o;
}

// ---------------- GEMM: out = relu(A @ W + bias), + bn stats ----------------
template<int K, int NWTOT, bool CONCAT, bool AFFINE, bool BF16A, bool BF16OUT>
__global__ __launch_bounds__(256) void k_gemm_mlp(
    const void* __restrict__ A0v, const float* __restrict__ A1,
    const float* __restrict__ W,
    const float* __restrict__ scale, const float* __restrict__ shift,
    const float* __restrict__ bias,
    void* __restrict__ outv, float* __restrict__ gstats, int nrows)
{
  __shared__ float As[32*68];
  __shared__ float Bs[32*128];
  __shared__ float s_sum[128], s_sq[128];
  int m0 = blockIdx.x*64;
  int n0 = blockIdx.y*128;
  int tid  = threadIdx.x;
  int tcol = tid & 31, trow = tid >> 5;
  float acc[8][4] = {};
  constexpr int NCH = (K + 31) / 32;
  for (int ch = 0; ch < NCH; ch++){
    int kc0 = ch*32;
    #pragma unroll
    for (int j = 0; j < 2; j++){
      int fid = tid + j*256;
      int rr = fid >> 3; int k4 = (fid & 7) << 2;
      int row = m0 + rr;
      int kg = kc0 + k4;
      float4 v = {0.f,0.f,0.f,0.f};
      if (row < nrows){
        if constexpr (BF16A){
          const uint16_t* Ab = (const uint16_t*)A0v;
          uint2 w = *(const uint2*)(Ab + (size_t)row*K + kg);
          bf2f2(w.x, v.x, v.y); bf2f2(w.y, v.z, v.w);
        } else if constexpr (CONCAT){
          const float* A0 = (const float*)A0v;
          if (kg < 256)      v = *(const float4*)(A0 + (size_t)row*256 + kg);
          else if (kg < 456) v = *(const float4*)(A1 + (size_t)row*200 + (kg-256));
        } else {
          const float* A0 = (const float*)A0v;
          v = *(const float4*)(A0 + (size_t)row*K + kg);
        }
      }
      if constexpr (AFFINE){
        float4 scv = *(const float4*)(scale + kg);
        float4 shv = *(const float4*)(shift + kg);
        v.x = fmaf(v.x, scv.x, shv.x);
        v.y = fmaf(v.y, scv.y, shv.y);
        v.z = fmaf(v.z, scv.z, shv.z);
        v.w = fmaf(v.w, scv.w, shv.w);
      }
      As[(k4+0)*68 + rr] = v.x;
      As[(k4+1)*68 + rr] = v.y;
      As[(k4+2)*68 + rr] = v.z;
      As[(k4+3)*68 + rr] = v.w;
    }
    #pragma unroll
    for (int j = 0; j < 4; j++){
      int fid = tid + j*256;
      int kk = fid >> 5; int c4 = (fid & 31) << 2;
      int kg = kc0 + kk;
      float4 v = {0.f,0.f,0.f,0.f};
      if (kg < K) v = *(const float4*)(W + (size_t)kg*NWTOT + n0 + c4);
      *(float4*)(Bs + kk*128 + c4) = v;
    }
    __syncthreads();
    #pragma unroll
    for (int kk = 0; kk < 32; kk++){
      float4 b  = *(const float4*)(Bs + kk*128 + tcol*4);
      float4 a0 = *(const float4*)(As + kk*68 + trow*8);
      float4 a1 = *(const float4*)(As + kk*68 + trow*8 + 4);
      float a[8] = {a0.x,a0.y,a0.z,a0.w,a1.x,a1.y,a1.z,a1.w};
      #pragma unroll
      for (int r = 0; r < 8; r++){
        acc[r][0] = fmaf(a[r], b.x, acc[r][0]);
        acc[r][1] = fmaf(a[r], b.y, acc[r][1]);
        acc[r][2] = fmaf(a[r], b.z, acc[r][2]);
        acc[r][3] = fmaf(a[r], b.w, acc[r][3]);
      }
    }
    __syncthreads();
  }
  for (int i = tid; i < 128; i += 256){ s_sum[i] = 0.f; s_sq[i] = 0.f; }
  __syncthreads();
  float4 bv = *(const float4*)(bias + n0 + tcol*4);
  float psum[4] = {0,0,0,0}, psq[4] = {0,0,0,0};
  #pragma unroll
  for (int r = 0; r < 8; r++){
    int row = m0 + trow*8 + r;
    if (row < nrows){
      float4 o;
      o.x = fmaxf(acc[r][0] + bv.x, 0.f);
      o.y = fmaxf(acc[r][1] + bv.y, 0.f);
      o.z = fmaxf(acc[r][2] + bv.z, 0.f);
      o.w = fmaxf(acc[r][3] + bv.w, 0.f);
      if constexpr (BF16OUT){
        uint16_t* op = (uint16_t*)outv;
        uint2 w; w.x = pack2bf(o.x, o.y); w.y = pack2bf(o.z, o.w);
        *(uint2*)(op + (size_t)row*NWTOT + n0 + tcol*4) = w;
      } else {
        float* op = (float*)outv;
        *(float4*)(op + (size_t)row*NWTOT + n0 + tcol*4) = o;
      }
      psum[0] += o.x; psq[0] += o.x*o.x;
      psum[1] += o.y; psq[1] += o.y*o.y;
      psum[2] += o.z; psq[2] += o.z*o.z;
      psum[3] += o.w; psq[3] += o.w*o.w;
    }
  }
  int f0 = tcol*4;
  atomicAdd(&s_sum[f0+0], psum[0]); atomicAdd(&s_sq[f0+0], psq[0]);
  atomicAdd(&s_sum[f0+1], psum[1]); atomicAdd(&s_sq[f0+1], psq[1]);
  atomicAdd(&s_sum[f0+2], psum[2]); atomicAdd(&s_sq[f0+2], psq[2]);
  atomicAdd(&s_sum[f0+3], psum[3]); atomicAdd(&s_sq[f0+3], psq[3]);
  __syncthreads();
  float* gs = gstats + (size_t)(blockIdx.x & 31)*(2*NWTOT);
  for (int i = tid; i < 128; i += 256){
    atomicAdd(&gs[n0 + i], s_sum[i]);
    atomicAdd(&gs[NWTOT + n0 + i], s_sq[i]);
  }
}

// ---------------- GEMM + fused relu/pool/stats (h2 never materialized) ----------------
template<int K, int NWTOT>
__global__ __launch_bounds__(256) void k_gemm_pool(
    const uint16_t* __restrict__ A, const float* __restrict__ W,
    const float* __restrict__ bias, const int* __restrict__ batch,
    float* __restrict__ embsum, float* __restrict__ gstats, int nrows)
{
  __shared__ float As[32*68];
  __shared__ float Bs[32*128];
  __shared__ float s_sum[128], s_sq[128];
  __shared__ int s_batch[64];
  int m0 = blockIdx.x*64;
  int n0 = blockIdx.y*128;
  int tid  = threadIdx.x;
  int tcol = tid & 31, trow = tid >> 5;
  float acc[8][4] = {};
  constexpr int NCH = (K + 31) / 32;
  for (int ch = 0; ch < NCH; ch++){
    int kc0 = ch*32;
    #pragma unroll
    for (int j = 0; j < 2; j++){
      int fid = tid + j*256;
      int rr = fid >> 3; int k4 = (fid & 7) << 2;
      int row = m0 + rr;
      int kg = kc0 + k4;
      float4 v = {0.f,0.f,0.f,0.f};
      if (row < nrows){
        uint2 w = *(const uint2*)(A + (size_t)row*K + kg);
        bf2f2(w.x, v.x, v.y); bf2f2(w.y, v.z, v.w);
      }
      As[(k4+0)*68 + rr] = v.x;
      As[(k4+1)*68 + rr] = v.y;
      As[(k4+2)*68 + rr] = v.z;
      As[(k4+3)*68 + rr] = v.w;
    }
    #pragma unroll
    for (int j = 0; j < 4; j++){
      int fid = tid + j*256;
      int kk = fid >> 5; int c4 = (fid & 31) << 2;
      int kg = kc0 + kk;
      float4 v = *(const float4*)(W + (size_t)kg*NWTOT + n0 + c4);
      *(float4*)(Bs + kk*128 + c4) = v;
    }
    __syncthreads();
    #pragma unroll
    for (int kk = 0; kk < 32; kk++){
      float4 b  = *(const float4*)(Bs + kk*128 + tcol*4);
      float4 a0 = *(const float4*)(As + kk*68 + trow*8);
      float4 a1 = *(const float4*)(As + kk*68 + trow*8 + 4);
      float a[8] = {a0.x,a0.y,a0.z,a0.w,a1.x,a1.y,a1.z,a1.w};
      #pragma unroll
      for (int r = 0; r < 8; r++){
        acc[r][0] = fmaf(a[r], b.x, acc[r][0]);
        acc[r][1] = fmaf(a[r], b.y, acc[r][1]);
        acc[r][2] = fmaf(a[r], b.z, acc[r][2]);
        acc[r][3] = fmaf(a[r], b.w, acc[r][3]);
      }
    }
    __syncthreads();
  }
  if (tid < 64) s_batch[tid] = (m0 + tid < nrows) ? batch[m0 + tid] : -1;
  for (int i = tid; i < 128; i += 256){ s_sum[i] = 0.f; s_sq[i] = 0.f; }
  __syncthreads();
  float4 bv = *(const float4*)(bias + n0 + tcol*4);
  float psum[4] = {0,0,0,0}, psq[4] = {0,0,0,0};
  float run[4] = {0,0,0,0};
  int runb = -1;
  #pragma unroll
  for (int r = 0; r < 8; r++){
    int row = m0 + trow*8 + r;
    if (row < nrows){
      float ox = fmaxf(acc[r][0] + bv.x, 0.f);
      float oy = fmaxf(acc[r][1] + bv.y, 0.f);
      float oz = fmaxf(acc[r][2] + bv.z, 0.f);
      float ow = fmaxf(acc[r][3] + bv.w, 0.f);
      psum[0] += ox; psq[0] += ox*ox;
      psum[1] += oy; psq[1] += oy*oy;
      psum[2] += oz; psq[2] += oz*oz;
      psum[3] += ow; psq[3] += ow*ow;
      int b = s_batch[trow*8 + r];
      if (b != runb){
        if (runb >= 0){
          float* es = embsum + (size_t)runb*NWTOT + n0 + tcol*4;
          atomicAdd(es+0, run[0]); atomicAdd(es+1, run[1]);
          atomicAdd(es+2, run[2]); atomicAdd(es+3, run[3]);
        }
        runb = b;
        run[0] = ox; run[1] = oy; run[2] = oz; run[3] = ow;
      } else {
        run[0] += ox; run[1] += oy; run[2] += oz; run[3] += ow;
      }
    }
  }
  if (runb >= 0){
    float* es = embsum + (size_t)runb*NWTOT + n0 + tcol*4;
    atomicAdd(es+0, run[0]); atomicAdd(es+1, run[1]);
    atomicAdd(es+2, run[2]); atomicAdd(es+3, run[3]);
  }
  int f0 = tcol*4;
  atomicAdd(&s_sum[f0+0], psum[0]); atomicAdd(&s_sq[f0+0], psq[0]);
  atomicAdd(&s_sum[f0+1], psum[1]); atomicAdd(&s_sq[f0+1], psq[1]);
  atomicAdd(&s_sum[f0+2], psum[2]); atomicAdd(&s_sq[f0+2], psq[2]);
  atomicAdd(&s_sum[f0+3], psum[3]); atomicAdd(&s_sq[f0+3], psq[3]);
  __syncthreads();
  float* gs = gstats + (size_t)(blockIdx.x & 31)*(2*NWTOT);
  for (int i = tid; i < 128; i += 256){
    atomicAdd(&gs[n0 + i], s_sum[i]);
    atomicAdd(&gs[NWTOT + n0 + i], s_sq[i]);
  }
}

// ---------------- final: out[g] = bn4(a2[g,:]) . mW3 + mb3 ----------------
__global__ __launch_bounds__(256) void k_final(
    const float* __restrict__ a2, const float* __restrict__ sc, const float* __restrict__ sh,
    const float* __restrict__ w, const float* __restrict__ b, float* __restrict__ out, int G)
{
  int gid  = blockIdx.x*blockDim.x + threadIdx.x;
  int wid  = gid >> 6;
  int lane = gid & 63;
  if (wid >= G) return;
  float2 v = ((const float2*)(a2 + (size_t)wid*128))[lane];
  int k = lane*2;
  float s = fmaf(v.x, sc[k], sh[k]) * w[k] + fmaf(v.y, sc[k+1], sh[k+1]) * w[k+1];
  #pragma unroll
  for (int o = 32; o > 0; o >>= 1) s += __shfl_down(s, o, 64);
  if (lane == 0) out[wid] = s + b[0];
}

// ---------------- launcher ----------------
extern "C" void kernel_launch(void* const* d_in, const int* in_sizes, int n_in,
                              void* d_out, int out_size, void* d_ws, size_t ws_size,
                              hipStream_t stream)
{
  (void)n_in; (void)out_size; (void)ws_size;
  const float* x    = (const float*)d_in[0];
  const int*   ei   = (const int*)d_in[1];
  const int*   batch= (const int*)d_in[2];
  const float* rdk  = (const float*)d_in[3];
  const float* W1   = (const float*)d_in[4];
  const float* b1   = (const float*)d_in[5];
  const float* g1   = (const float*)d_in[6];
  const float* be1  = (const float*)d_in[7];
  const float* W2   = (const float*)d_in[8];
  const float* b2   = (const float*)d_in[9];
  const float* g2   = (const float*)d_in[10];
  const float* be2  = (const float*)d_in[11];
  const float* mW1  = (const float*)d_in[12];
  const float* mb1  = (const float*)d_in[13];
  const float* mg1  = (const float*)d_in[14];
  const float* mbe1 = (const float*)d_in[15];
  const float* mW2  = (const float*)d_in[16];
  const float* mb2  = (const float*)d_in[17];
  const float* mg2  = (const float*)d_in[18];
  const float* mbe2 = (const float*)d_in[19];
  const float* mW3  = (const float*)d_in[20];
  const float* mb3  = (const float*)d_in[21];

  const int N = in_sizes[0] / 64;
  const int E = in_sizes[1] / 2;
  const int G = in_sizes[3] / 200;
  const int* erow = ei;
  const int* ecol = ei + E;
  const int nb = (N + 511) >> 9;   // 512-node buckets

  size_t off = 0;
  auto alloc = [&](size_t bytes)->char*{
    char* p = (char*)d_ws + off;
    off += (bytes + 255) & ~(size_t)255;
    return p;
  };
  int*   indeg  = (int*)  alloc((size_t)N*4);
  int*   offs   = (int*)  alloc(((size_t)N+1)*4);
  int*   csr    = (int*)  alloc((size_t)E*4);
  uint2* ebuf   = (uint2*)alloc((size_t)E*8);
  int*   bcur   = (int*)  alloc(256*4);
  float* dinv   = (float*)alloc((size_t)N*4);
  int*   bsum   = (int*)  alloc(1024*4);
  uint16_t* xs  = (uint16_t*)alloc((size_t)N*64*2);
  uint16_t* z1  = (uint16_t*)alloc((size_t)N*64*2);
  uint16_t* h1  = (uint16_t*)alloc((size_t)N*128*2);
  uint16_t* hs  = (uint16_t*)alloc((size_t)N*128*2);
  uint16_t* z2  = (uint16_t*)alloc((size_t)N*128*2);
  float* embsum = (float*)alloc((size_t)G*256*4);
  int*   cnt    = (int*)  alloc((size_t)G*4);
  float* emb    = (float*)alloc((size_t)G*256*4);
  float* a1     = (float*)alloc((size_t)G*256*4);
  float* a2     = (float*)alloc((size_t)G*128*4);
  float* gstats = (float*)alloc((size_t)4*32*2*256*4);
  float* scsh   = (float*)alloc((size_t)4*2*256*4);

  float* gs0 = gstats;
  float* gs1 = gstats + 32*2*256;
  float* gs2 = gstats + 2*32*2*256;
  float* gs3 = gstats + 3*32*2*256;
  float* sc1 = scsh;        float* sh1 = scsh + 256;
  float* sc2 = scsh + 512;  float* sh2 = scsh + 768;
  float* sc3 = scsh + 1024; float* sh3 = scsh + 1280;
  float* sc4 = scsh + 1536; float* sh4 = scsh + 1792;

  hipMemsetAsync(indeg,  0, (size_t)N*4, stream);
  hipMemsetAsync(gstats, 0, (size_t)4*32*2*256*4, stream);
  hipMemsetAsync(embsum, 0, (size_t)G*256*4, stream);
  hipMemsetAsync(cnt,    0, (size_t)G*4, stream);

  int nblkE = (E + 255) / 256;
  int nblkN = (N + 255) / 256;
  int nscan = (N + 1023) / 1024;
  int mblk  = (N + 63) / 64;
  int gblk  = (G + 63) / 64;

  // CSR build: count -> scan -> histogram-partition (pass A) -> bucket fill (pass B)
  k_count<<<nblkE,256,0,stream>>>(ecol, indeg, E);
  k_scan1<<<nscan,256,0,stream>>>(indeg, offs, bsum, N);
  k_scan2<<<1,128,0,stream>>>(bsum, nscan);
  k_scan3<<<nblkN,256,0,stream>>>(offs, bsum, N, E);
  k_dinv<<<nblkN,256,0,stream>>>(indeg, dinv, N);
  k_initbcur<<<1,256,0,stream>>>(offs, bcur, N);
  k_passA<<<(E + PA_TILE - 1)/PA_TILE,256,0,stream>>>(erow, ecol, bcur, ebuf, E);
  k_passB<<<nb,256,0,stream>>>(ebuf, offs, csr, N);
  k_cnt<<<nblkN,256,0,stream>>>(batch, cnt, N);

  // layer 1: aggregate-first (F=64), then GEMM 64->128 with fused relu+stats
  k_prep1<<<(N*16+255)/256,256,0,stream>>>((const float4*)x, dinv, (ushort4*)xs, N);
  k_agg1<<<(N+31)/32,256,0,stream>>>((const uint4*)xs, offs, csr, dinv, (uint4*)z1, N);
  k_gemm_mlp<64,128,false,false,true,true><<<dim3(mblk,1),256,0,stream>>>(z1, nullptr, W1, nullptr, nullptr, b1, h1, gs0, N);
  k_bnfin<<<1,256,0,stream>>>(gs0, 128, 1.0f/(float)N, g1, be1, sc1, sh1);

  // layer 2: fold bn1 affine + dinv into bf16 payload, aggregate (F=128), GEMM 128->256 + fused pool
  k_prep2<<<(N*32+255)/256,256,0,stream>>>((const uint2*)h1, dinv, (const float4*)sc1, (const float4*)sh1, (ushort4*)hs, N);
  k_agg2<<<(N+15)/16,256,0,stream>>>((const uint4*)hs, offs, csr, dinv, (uint4*)z2, N);
  k_gemm_pool<128,256><<<dim3(mblk,2),256,0,stream>>>(z2, W2, b2, batch, embsum, gs1, N);
  k_bnfin<<<1,256,0,stream>>>(gs1, 256, 1.0f/(float)N, g2, be2, sc2, sh2);

  // graph head
  k_emb<<<(G*64+255)/256,256,0,stream>>>(embsum, cnt, sc2, sh2, emb, G);
  k_gemm_mlp<456,256,true,false,false,false><<<dim3(gblk,2),256,0,stream>>>(emb, rdk, mW1, nullptr, nullptr, mb1, a1, gs2, G);
  k_bnfin<<<1,256,0,stream>>>(gs2, 256, 1.0f/(float)G, mg1, mbe1, sc3, sh3);
  k_gemm_mlp<256,128,false,true,false,false><<<dim3(gblk,1),256,0,stream>>>(a1, nullptr, mW2, sc3, sh3, mb2, a2, gs3, G);
  k_bnfin<<<1,256,0,stream>>>(gs3, 128, 1.0f/(float)G, mg2, mbe2, sc4, sh4);
  k_final<<<(G+3)/4,256,0,stream>>>(a2, sc4, sh4, mW3, mb3, (float*)d_out, G);
}

// Round 5
// 694.345 us; speedup vs baseline: 1.7790x; 1.1694x over previous
//
#include <hip/hip_runtime.h>
#include <cstdint>
#include <cstddef>

#define BN_EPS 1e-5f

// ---------------- helpers ----------------

__device__ inline uint16_t f2bf(float f){
  union {float f; uint32_t u;} v; v.f = f;
  uint32_t u = v.u;
  return (uint16_t)((u + 0x7FFFu + ((u >> 16) & 1u)) >> 16);
}

__device__ inline uint32_t pack2bf(float a, float b){
  return (uint32_t)f2bf(a) | ((uint32_t)f2bf(b) << 16);
}

__device__ inline void bf2f2(uint32_t w, float& a, float& b){
  union {uint32_t u; float f;} ua, ub;
  ua.u = w << 16; ub.u = w & 0xFFFF0000u;
  a = ua.f; b = ub.f;
}

// ---------------- graph preprocessing ----------------
// bucket = col >> 9 (512 nodes per bucket), nb <= 256 buckets.

#define PA_TILE 4096

// per-block LDS histogram of buckets -> global bucket counts (few atomics)
__global__ __launch_bounds__(256) void k_hist(const int* __restrict__ col,
                                              int* __restrict__ bcnt, int E){
  __shared__ int h[256];
  int t = threadIdx.x;
  int start = blockIdx.x * PA_TILE;
  h[t] = 0;
  __syncthreads();
  #pragma unroll
  for (int j = 0; j < 16; j++){
    int e = start + t + j*256;
    if (e < E) atomicAdd(&h[col[e] >> 9], 1);
  }
  __syncthreads();
  if (h[t] > 0) atomicAdd(&bcnt[t], h[t]);
}

// single-block exclusive scan of 256 bucket counts -> bbase[257] and gcur
__global__ __launch_bounds__(256) void k_bscan(const int* __restrict__ bcnt,
                                               int* __restrict__ bbase,
                                               int* __restrict__ gcur, int E){
  __shared__ int s[256];
  int t = threadIdx.x;
  int v = bcnt[t];
  s[t] = v;
  __syncthreads();
  for (int off=1; off<256; off<<=1){
    int x = 0;
    if (t >= off) x = s[t-off];
    __syncthreads();
    if (t >= off) s[t] += x;
    __syncthreads();
  }
  int excl = s[t] - v;
  bbase[t] = excl;
  gcur[t]  = excl;
  if (t == 255) bbase[256] = E;
}

// pass A: block-private histogram partition of edges into 512-node buckets.
__global__ __launch_bounds__(256) void k_passA(
    const int* __restrict__ row, const int* __restrict__ col,
    int* __restrict__ gcur, uint2* __restrict__ ebuf, int E)
{
  __shared__ int hist[256];
  __shared__ int rbase[256];
  int t = threadIdx.x;
  int start = blockIdx.x * PA_TILE;
  hist[t] = 0;
  __syncthreads();
  int myr[16], myc[16], myb[16];
  #pragma unroll
  for (int j = 0; j < 16; j++){
    int e = start + t + j*256;
    if (e < E){
      int r = row[e], c = col[e];
      myr[j] = r; myc[j] = c; myb[j] = c >> 9;
      atomicAdd(&hist[myb[j]], 1);
    } else myb[j] = -1;
  }
  __syncthreads();
  {
    int h = hist[t];
    rbase[t] = (h > 0) ? atomicAdd(&gcur[t], h) : 0;
  }
  __syncthreads();
  hist[t] = 0;
  __syncthreads();
  #pragma unroll
  for (int j = 0; j < 16; j++){
    if (myb[j] >= 0){
      int pos = rbase[myb[j]] + atomicAdd(&hist[myb[j]], 1);
      uint2 rc; rc.x = (unsigned)myr[j]; rc.y = (unsigned)myc[j];
      ebuf[pos] = rc;
    }
  }
}

// pass B2 (fused): per-bucket degree histogram -> offs + dinv + CSR scatter
__global__ __launch_bounds__(256) void k_passB2(
    const uint2* __restrict__ ebuf, const int* __restrict__ bbase,
    int* __restrict__ offs, float* __restrict__ dinv,
    int* __restrict__ csr, int N, int E, int nb)
{
  __shared__ int deg[512];
  __shared__ int cur[512];
  __shared__ int ps[256];
  int b = blockIdx.x;
  int base = b << 9;
  int t = threadIdx.x;
  int s = bbase[b], e = bbase[b+1];
  deg[t] = 0; deg[t+256] = 0;
  __syncthreads();
  for (int i = s + t; i < e; i += 256)
    atomicAdd(&deg[(int)ebuf[i].y - base], 1);
  __syncthreads();
  int d0 = deg[2*t], d1 = deg[2*t+1];
  int pair = d0 + d1;
  ps[t] = pair;
  __syncthreads();
  for (int off=1; off<256; off<<=1){
    int x = 0;
    if (t >= off) x = ps[t-off];
    __syncthreads();
    if (t >= off) ps[t] += x;
    __syncthreads();
  }
  int excl = ps[t] - pair;
  int o0 = s + excl;
  int o1 = o0 + d0;
  int n0 = base + 2*t, n1 = base + 2*t + 1;
  cur[2*t] = o0; cur[2*t+1] = o1;
  if (n0 < N){ offs[n0] = o0; dinv[n0] = 1.0f / sqrtf((float)(d0 + 1)); }
  if (n1 < N){ offs[n1] = o1; dinv[n1] = 1.0f / sqrtf((float)(d1 + 1)); }
  if (b == nb-1 && t == 0) offs[N] = E;
  __syncthreads();
  for (int i = s + t; i < e; i += 256){
    uint2 rc = ebuf[i];
    int local = (int)rc.y - base;
    int pos = atomicAdd(&cur[local], 1);
    csr[pos] = (int)rc.x;
  }
}

__global__ void k_cnt(const int* __restrict__ batch, int* __restrict__ cnt, int n){
  int i = blockIdx.x*blockDim.x + threadIdx.x;
  if (i < n) atomicAdd(&cnt[batch[i]], 1);
}

// per-column bn finalize: scale = g*rstd, shift = be - mu*scale
__global__ void k_bnfin(const float* __restrict__ region, int F, float invCount,
                        const float* __restrict__ g, const float* __restrict__ be,
                        float* __restrict__ scale, float* __restrict__ shift){
  int i = blockIdx.x*blockDim.x + threadIdx.x;
  if (i >= F) return;
  float s = 0.f, q = 0.f;
  for (int sl = 0; sl < 32; sl++){
    s += region[sl*2*F + i];
    q += region[sl*2*F + F + i];
  }
  float mu  = s * invCount;
  float var = q * invCount - mu*mu;
  if (var < 0.f) var = 0.f;
  float rstd = 1.0f / sqrtf(var + BN_EPS);
  float sc = g[i] * rstd;
  scale[i] = sc;
  shift[i] = be[i] - mu * sc;
}

// xs = bf16(x * dinv[node]) : N x 64
__global__ void k_prep1(const float4* __restrict__ x, const float* __restrict__ dinv,
                        ushort4* __restrict__ xs, int N){
  int id = blockIdx.x*blockDim.x + threadIdx.x;
  if (id >= N*16) return;
  int row = id >> 4;
  float d = dinv[row];
  float4 v = x[id];
  ushort4 o;
  o.x = f2bf(v.x*d); o.y = f2bf(v.y*d); o.z = f2bf(v.z*d); o.w = f2bf(v.w*d);
  xs[id] = o;
}

// hs = bf16((bf16(h1)*sc1 + sh1) * dinv[node]) : N x 128
__global__ void k_prep2(const uint2* __restrict__ h1, const float* __restrict__ dinv,
                        const float4* __restrict__ sc, const float4* __restrict__ sh,
                        ushort4* __restrict__ hs, int N){
  int id = blockIdx.x*blockDim.x + threadIdx.x;
  if (id >= N*32) return;
  int row = id >> 5, lane = id & 31;
  float d = dinv[row];
  uint2 w = h1[id];
  float f0,f1,f2,f3;
  bf2f2(w.x, f0, f1); bf2f2(w.y, f2, f3);
  float4 s4 = sc[lane], h4 = sh[lane];
  ushort4 o;
  o.x = f2bf(fmaf(f0, s4.x, h4.x)*d);
  o.y = f2bf(fmaf(f1, s4.y, h4.y)*d);
  o.z = f2bf(fmaf(f2, s4.z, h4.z)*d);
  o.w = f2bf(fmaf(f3, s4.w, h4.w)*d);
  hs[id] = o;
}

// emb[g,:] = (cnt>0) ? mean * scale2 + shift2 : 0
__global__ void k_emb(const float* __restrict__ embsum, const int* __restrict__ cnt,
                      const float* __restrict__ sc, const float* __restrict__ sh,
                      float* __restrict__ emb, int G){
  int id = blockIdx.x*blockDim.x + threadIdx.x;
  if (id >= G*64) return;
  int g = id >> 6, l = id & 63;
  float4 s = ((const float4*)embsum)[id];
  int c = cnt[g];
  float4 o = {0.f,0.f,0.f,0.f};
  if (c > 0){
    float inv = 1.0f / (float)c;
    int k = l*4;
    o.x = fmaf(s.x*inv, sc[k+0], sh[k+0]);
    o.y = fmaf(s.y*inv, sc[k+1], sh[k+1]);
    o.z = fmaf(s.z*inv, sc[k+2], sh[k+2]);
    o.w = fmaf(s.w*inv, sc[k+3], sh[k+3]);
  }
  ((float4*)emb)[id] = o;
}

// ---------------- aggregation (gather) kernels, bf16 in / bf16 out ----------------
// agg1: z1[c,:] = bf16(dinv[c] * (sum xs[r,:] + xs[c,:])), F=64, 8 lanes/node
__global__ __launch_bounds__(256) void k_agg1(
    const uint4* __restrict__ xs, const int* __restrict__ offs, const int* __restrict__ csr,
    const float* __restrict__ dinv, uint4* __restrict__ z, int N)
{
  int sub = threadIdx.x >> 3, lane = threadIdx.x & 7;
  int node = blockIdx.x*32 + sub;
  if (node >= N) return;
  int s = offs[node], e = offs[node+1];
  float acc[8] = {};
  auto add8 = [&](uint4 v){
    float f0,f1,f2,f3,f4,f5,f6,f7;
    bf2f2(v.x, f0, f1); bf2f2(v.y, f2, f3);
    bf2f2(v.z, f4, f5); bf2f2(v.w, f6, f7);
    acc[0]+=f0; acc[1]+=f1; acc[2]+=f2; acc[3]+=f3;
    acc[4]+=f4; acc[5]+=f5; acc[6]+=f6; acc[7]+=f7;
  };
  int i = s;
  for (; i + 2 <= e; i += 2){
    int r0 = csr[i], r1 = csr[i+1];
    uint4 v0 = xs[r0*8 + lane];
    uint4 v1 = xs[r1*8 + lane];
    add8(v0); add8(v1);
  }
  if (i < e) add8(xs[csr[i]*8 + lane]);
  add8(xs[node*8 + lane]);
  float d = dinv[node];
  uint4 o;
  o.x = pack2bf(acc[0]*d, acc[1]*d);
  o.y = pack2bf(acc[2]*d, acc[3]*d);
  o.z = pack2bf(acc[4]*d, acc[5]*d);
  o.w = pack2bf(acc[6]*d, acc[7]*d);
  z[node*8 + lane] = o;
}

// agg2: z2[c,:] = bf16(dinv[c] * (sum hs[r,:] + hs[c,:])), F=128, 16 lanes/node
__global__ __launch_bounds__(256) void k_agg2(
    const uint4* __restrict__ hs, const int* __restrict__ offs, const int* __restrict__ csr,
    const float* __restrict__ dinv, uint4* __restrict__ z, int N)
{
  int sub = threadIdx.x >> 4, lane = threadIdx.x & 15;
  int node = blockIdx.x*16 + sub;
  if (node >= N) return;
  int s = offs[node], e = offs[node+1];
  float acc[8] = {};
  auto add8 = [&](uint4 v){
    float f0,f1,f2,f3,f4,f5,f6,f7;
    bf2f2(v.x, f0, f1); bf2f2(v.y, f2, f3);
    bf2f2(v.z, f4, f5); bf2f2(v.w, f6, f7);
    acc[0]+=f0; acc[1]+=f1; acc[2]+=f2; acc[3]+=f3;
    acc[4]+=f4; acc[5]+=f5; acc[6]+=f6; acc[7]+=f7;
  };
  int i = s;
  for (; i + 2 <= e; i += 2){
    int r0 = csr[i], r1 = csr[i+1];
    uint4 v0 = hs[r0*16 + lane];
    uint4 v1 = hs[r1*16 + lane];
    add8(v0); add8(v1);
  }
  if (i < e) add8(hs[csr[i]*16 + lane]);
  add8(hs[node*16 + lane]);
  float d = dinv[node];
  uint4 o;
  o.x = pack2bf(acc[0]*d, acc[1]*d);
  o.y = pack2bf(acc[2]*d, acc[3]*d);
  o.z = pack2bf(acc[4]*d, acc[5]*d);
  o.w = pack2bf(acc[6]*d, acc[7]*d);
  z[node*16 + lane] = o;
}

// ---------------- GEMM: out = relu(A @ W + bias), + bn stats ----------------
template<int K, int NWTOT, bool CONCAT, bool AFFINE, bool BF16A, bool BF16OUT>
__global__ __launch_bounds__(256) void k_gemm_mlp(
    const void* __restrict__ A0v, const float* __restrict__ A1,
    const float* __restrict__ W,
    const float* __restrict__ scale, const float* __restrict__ shift,
    const float* __restrict__ bias,
    void* __restrict__ outv, float* __restrict__ gstats, int nrows)
{
  __shared__ float As[32*68];
  __shared__ float Bs[32*128];
  __shared__ float s_sum[128], s_sq[128];
  int m0 = blockIdx.x*64;
  int n0 = blockIdx.y*128;
  int tid  = threadIdx.x;
  int tcol = tid & 31, trow = tid >> 5;
  float acc[8][4] = {};
  constexpr int NCH = (K + 31) / 32;
  for (int ch = 0; ch < NCH; ch++){
    int kc0 = ch*32;
    #pragma unroll
    for (int j = 0; j < 2; j++){
      int fid = tid + j*256;
      int rr = fid >> 3; int k4 = (fid & 7) << 2;
      int row = m0 + rr;
      int kg = kc0 + k4;
      float4 v = {0.f,0.f,0.f,0.f};
      if (row < nrows){
        if constexpr (BF16A){
          const uint16_t* Ab = (const uint16_t*)A0v;
          uint2 w = *(const uint2*)(Ab + (size_t)row*K + kg);
          bf2f2(w.x, v.x, v.y); bf2f2(w.y, v.z, v.w);
        } else if constexpr (CONCAT){
          const float* A0 = (const float*)A0v;
          if (kg < 256)      v = *(const float4*)(A0 + (size_t)row*256 + kg);
          else if (kg < 456) v = *(const float4*)(A1 + (size_t)row*200 + (kg-256));
        } else {
          const float* A0 = (const float*)A0v;
          v = *(const float4*)(A0 + (size_t)row*K + kg);
        }
      }
      if constexpr (AFFINE){
        float4 scv = *(const float4*)(scale + kg);
        float4 shv = *(const float4*)(shift + kg);
        v.x = fmaf(v.x, scv.x, shv.x);
        v.y = fmaf(v.y, scv.y, shv.y);
        v.z = fmaf(v.z, scv.z, shv.z);
        v.w = fmaf(v.w, scv.w, shv.w);
      }
      As[(k4+0)*68 + rr] = v.x;
      As[(k4+1)*68 + rr] = v.y;
      As[(k4+2)*68 + rr] = v.z;
      As[(k4+3)*68 + rr] = v.w;
    }
    #pragma unroll
    for (int j = 0; j < 4; j++){
      int fid = tid + j*256;
      int kk = fid >> 5; int c4 = (fid & 31) << 2;
      int kg = kc0 + kk;
      float4 v = {0.f,0.f,0.f,0.f};
      if (kg < K) v = *(const float4*)(W + (size_t)kg*NWTOT + n0 + c4);
      *(float4*)(Bs + kk*128 + c4) = v;
    }
    __syncthreads();
    #pragma unroll
    for (int kk = 0; kk < 32; kk++){
      float4 b  = *(const float4*)(Bs + kk*128 + tcol*4);
      float4 a0 = *(const float4*)(As + kk*68 + trow*8);
      float4 a1 = *(const float4*)(As + kk*68 + trow*8 + 4);
      float a[8] = {a0.x,a0.y,a0.z,a0.w,a1.x,a1.y,a1.z,a1.w};
      #pragma unroll
      for (int r = 0; r < 8; r++){
        acc[r][0] = fmaf(a[r], b.x, acc[r][0]);
        acc[r][1] = fmaf(a[r], b.y, acc[r][1]);
        acc[r][2] = fmaf(a[r], b.z, acc[r][2]);
        acc[r][3] = fmaf(a[r], b.w, acc[r][3]);
      }
    }
    __syncthreads();
  }
  for (int i = tid; i < 128; i += 256){ s_sum[i] = 0.f; s_sq[i] = 0.f; }
  __syncthreads();
  float4 bv = *(const float4*)(bias + n0 + tcol*4);
  float psum[4] = {0,0,0,0}, psq[4] = {0,0,0,0};
  #pragma unroll
  for (int r = 0; r < 8; r++){
    int row = m0 + trow*8 + r;
    if (row < nrows){
      float4 o;
      o.x = fmaxf(acc[r][0] + bv.x, 0.f);
      o.y = fmaxf(acc[r][1] + bv.y, 0.f);
      o.z = fmaxf(acc[r][2] + bv.z, 0.f);
      o.w = fmaxf(acc[r][3] + bv.w, 0.f);
      if constexpr (BF16OUT){
        uint16_t* op = (uint16_t*)outv;
        uint2 w; w.x = pack2bf(o.x, o.y); w.y = pack2bf(o.z, o.w);
        *(uint2*)(op + (size_t)row*NWTOT + n0 + tcol*4) = w;
      } else {
        float* op = (float*)outv;
        *(float4*)(op + (size_t)row*NWTOT + n0 + tcol*4) = o;
      }
      psum[0] += o.x; psq[0] += o.x*o.x;
      psum[1] += o.y; psq[1] += o.y*o.y;
      psum[2] += o.z; psq[2] += o.z*o.z;
      psum[3] += o.w; psq[3] += o.w*o.w;
    }
  }
  int f0 = tcol*4;
  atomicAdd(&s_sum[f0+0], psum[0]); atomicAdd(&s_sq[f0+0], psq[0]);
  atomicAdd(&s_sum[f0+1], psum[1]); atomicAdd(&s_sq[f0+1], psq[1]);
  atomicAdd(&s_sum[f0+2], psum[2]); atomicAdd(&s_sq[f0+2], psq[2]);
  atomicAdd(&s_sum[f0+3], psum[3]); atomicAdd(&s_sq[f0+3], psq[3]);
  __syncthreads();
  float* gs = gstats + (size_t)(blockIdx.x & 31)*(2*NWTOT);
  for (int i = tid; i < 128; i += 256){
    atomicAdd(&gs[n0 + i], s_sum[i]);
    atomicAdd(&gs[NWTOT + n0 + i], s_sq[i]);
  }
}

// ---------------- GEMM + fused relu/pool/stats (h2 never materialized) ----------------
template<int K, int NWTOT>
__global__ __launch_bounds__(256) void k_gemm_pool(
    const uint16_t* __restrict__ A, const float* __restrict__ W,
    const float* __restrict__ bias, const int* __restrict__ batch,
    float* __restrict__ embsum, float* __restrict__ gstats, int nrows)
{
  __shared__ float As[32*68];
  __shared__ float Bs[32*128];
  __shared__ float s_sum[128], s_sq[128];
  __shared__ int s_batch[64];
  int m0 = blockIdx.x*64;
  int n0 = blockIdx.y*128;
  int tid  = threadIdx.x;
  int tcol = tid & 31, trow = tid >> 5;
  float acc[8][4] = {};
  constexpr int NCH = (K + 31) / 32;
  for (int ch = 0; ch < NCH; ch++){
    int kc0 = ch*32;
    #pragma unroll
    for (int j = 0; j < 2; j++){
      int fid = tid + j*256;
      int rr = fid >> 3; int k4 = (fid & 7) << 2;
      int row = m0 + rr;
      int kg = kc0 + k4;
      float4 v = {0.f,0.f,0.f,0.f};
      if (row < nrows){
        uint2 w = *(const uint2*)(A + (size_t)row*K + kg);
        bf2f2(w.x, v.x, v.y); bf2f2(w.y, v.z, v.w);
      }
      As[(k4+0)*68 + rr] = v.x;
      As[(k4+1)*68 + rr] = v.y;
      As[(k4+2)*68 + rr] = v.z;
      As[(k4+3)*68 + rr] = v.w;
    }
    #pragma unroll
    for (int j = 0; j < 4; j++){
      int fid = tid + j*256;
      int kk = fid >> 5; int c4 = (fid & 31) << 2;
      int kg = kc0 + kk;
      float4 v = *(const float4*)(W + (size_t)kg*NWTOT + n0 + c4);
      *(float4*)(Bs + kk*128 + c4) = v;
    }
    __syncthreads();
    #pragma unroll
    for (int kk = 0; kk < 32; kk++){
      float4 b  = *(const float4*)(Bs + kk*128 + tcol*4);
      float4 a0 = *(const float4*)(As + kk*68 + trow*8);
      float4 a1 = *(const float4*)(As + kk*68 + trow*8 + 4);
      float a[8] = {a0.x,a0.y,a0.z,a0.w,a1.x,a1.y,a1.z,a1.w};
      #pragma unroll
      for (int r = 0; r < 8; r++){
        acc[r][0] = fmaf(a[r], b.x, acc[r][0]);
        acc[r][1] = fmaf(a[r], b.y, acc[r][1]);
        acc[r][2] = fmaf(a[r], b.z, acc[r][2]);
        acc[r][3] = fmaf(a[r], b.w, acc[r][3]);
      }
    }
    __syncthreads();
  }
  if (tid < 64) s_batch[tid] = (m0 + tid < nrows) ? batch[m0 + tid] : -1;
  for (int i = tid; i < 128; i += 256){ s_sum[i] = 0.f; s_sq[i] = 0.f; }
  __syncthreads();
  float4 bv = *(const float4*)(bias + n0 + tcol*4);
  float psum[4] = {0,0,0,0}, psq[4] = {0,0,0,0};
  float run[4] = {0,0,0,0};
  int runb = -1;
  #pragma unroll
  for (int r = 0; r < 8; r++){
    int row = m0 + trow*8 + r;
    if (row < nrows){
      float ox = fmaxf(acc[r][0] + bv.x, 0.f);
      float oy = fmaxf(acc[r][1] + bv.y, 0.f);
      float oz = fmaxf(acc[r][2] + bv.z, 0.f);
      float ow = fmaxf(acc[r][3] + bv.w, 0.f);
      psum[0] += ox; psq[0] += ox*ox;
      psum[1] += oy; psq[1] += oy*oy;
      psum[2] += oz; psq[2] += oz*oz;
      psum[3] += ow; psq[3] += ow*ow;
      int b = s_batch[trow*8 + r];
      if (b != runb){
        if (runb >= 0){
          float* es = embsum + (size_t)runb*NWTOT + n0 + tcol*4;
          atomicAdd(es+0, run[0]); atomicAdd(es+1, run[1]);
          atomicAdd(es+2, run[2]); atomicAdd(es+3, run[3]);
        }
        runb = b;
        run[0] = ox; run[1] = oy; run[2] = oz; run[3] = ow;
      } else {
        run[0] += ox; run[1] += oy; run[2] += oz; run[3] += ow;
      }
    }
  }
  if (runb >= 0){
    float* es = embsum + (size_t)runb*NWTOT + n0 + tcol*4;
    atomicAdd(es+0, run[0]); atomicAdd(es+1, run[1]);
    atomicAdd(es+2, run[2]); atomicAdd(es+3, run[3]);
  }
  int f0 = tcol*4;
  atomicAdd(&s_sum[f0+0], psum[0]); atomicAdd(&s_sq[f0+0], psq[0]);
  atomicAdd(&s_sum[f0+1], psum[1]); atomicAdd(&s_sq[f0+1], psq[1]);
  atomicAdd(&s_sum[f0+2], psum[2]); atomicAdd(&s_sq[f0+2], psq[2]);
  atomicAdd(&s_sum[f0+3], psum[3]); atomicAdd(&s_sq[f0+3], psq[3]);
  __syncthreads();
  float* gs = gstats + (size_t)(blockIdx.x & 31)*(2*NWTOT);
  for (int i = tid; i < 128; i += 256){
    atomicAdd(&gs[n0 + i], s_sum[i]);
    atomicAdd(&gs[NWTOT + n0 + i], s_sq[i]);
  }
}

// ---------------- final: out[g] = bn4(a2[g,:]) . mW3 + mb3 ----------------
__global__ __launch_bounds__(256) void k_final(
    const float* __restrict__ a2, const float* __restrict__ sc, const float* __restrict__ sh,
    const float* __restrict__ w, const float* __restrict__ b, float* __restrict__ out, int G)
{
  int gid  = blockIdx.x*blockDim.x + threadIdx.x;
  int wid  = gid >> 6;
  int lane = gid & 63;
  if (wid >= G) return;
  float2 v = ((const float2*)(a2 + (size_t)wid*128))[lane];
  int k = lane*2;
  float s = fmaf(v.x, sc[k], sh[k]) * w[k] + fmaf(v.y, sc[k+1], sh[k+1]) * w[k+1];
  #pragma unroll
  for (int o = 32; o > 0; o >>= 1) s += __shfl_down(s, o, 64);
  if (lane == 0) out[wid] = s + b[0];
}

// ---------------- launcher ----------------
extern "C" void kernel_launch(void* const* d_in, const int* in_sizes, int n_in,
                              void* d_out, int out_size, void* d_ws, size_t ws_size,
                              hipStream_t stream)
{
  (void)n_in; (void)out_size; (void)ws_size;
  const float* x    = (const float*)d_in[0];
  const int*   ei   = (const int*)d_in[1];
  const int*   batch= (const int*)d_in[2];
  const float* rdk  = (const float*)d_in[3];
  const float* W1   = (const float*)d_in[4];
  const float* b1   = (const float*)d_in[5];
  const float* g1   = (const float*)d_in[6];
  const float* be1  = (const float*)d_in[7];
  const float* W2   = (const float*)d_in[8];
  const float* b2   = (const float*)d_in[9];
  const float* g2   = (const float*)d_in[10];
  const float* be2  = (const float*)d_in[11];
  const float* mW1  = (const float*)d_in[12];
  const float* mb1  = (const float*)d_in[13];
  const float* mg1  = (const float*)d_in[14];
  const float* mbe1 = (const float*)d_in[15];
  const float* mW2  = (const float*)d_in[16];
  const float* mb2  = (const float*)d_in[17];
  const float* mg2  = (const float*)d_in[18];
  const float* mbe2 = (const float*)d_in[19];
  const float* mW3  = (const float*)d_in[20];
  const float* mb3  = (const float*)d_in[21];

  const int N = in_sizes[0] / 64;
  const int E = in_sizes[1] / 2;
  const int G = in_sizes[3] / 200;
  const int* erow = ei;
  const int* ecol = ei + E;
  const int nb = (N + 511) >> 9;   // 512-node buckets

  size_t off = 0;
  auto alloc = [&](size_t bytes)->char*{
    char* p = (char*)d_ws + off;
    off += (bytes + 255) & ~(size_t)255;
    return p;
  };
  int*   offs   = (int*)  alloc(((size_t)N+1)*4);
  int*   csr    = (int*)  alloc((size_t)E*4);
  uint2* ebuf   = (uint2*)alloc((size_t)E*8);
  int*   bcnt   = (int*)  alloc(256*4);
  int*   bbase  = (int*)  alloc(257*4);
  int*   bcur   = (int*)  alloc(256*4);
  float* dinv   = (float*)alloc((size_t)N*4);
  uint16_t* xs  = (uint16_t*)alloc((size_t)N*64*2);
  uint16_t* z1  = (uint16_t*)alloc((size_t)N*64*2);
  uint16_t* h1  = (uint16_t*)alloc((size_t)N*128*2);
  uint16_t* hs  = (uint16_t*)alloc((size_t)N*128*2);
  uint16_t* z2  = (uint16_t*)alloc((size_t)N*128*2);
  float* embsum = (float*)alloc((size_t)G*256*4);
  int*   cnt    = (int*)  alloc((size_t)G*4);
  float* emb    = (float*)alloc((size_t)G*256*4);
  float* a1     = (float*)alloc((size_t)G*256*4);
  float* a2     = (float*)alloc((size_t)G*128*4);
  float* gstats = (float*)alloc((size_t)4*32*2*256*4);
  float* scsh   = (float*)alloc((size_t)4*2*256*4);

  float* gs0 = gstats;
  float* gs1 = gstats + 32*2*256;
  float* gs2 = gstats + 2*32*2*256;
  float* gs3 = gstats + 3*32*2*256;
  float* sc1 = scsh;        float* sh1 = scsh + 256;
  float* sc2 = scsh + 512;  float* sh2 = scsh + 768;
  float* sc3 = scsh + 1024; float* sh3 = scsh + 1280;
  float* sc4 = scsh + 1536; float* sh4 = scsh + 1792;

  hipMemsetAsync(bcnt,   0, 256*4, stream);
  hipMemsetAsync(gstats, 0, (size_t)4*32*2*256*4, stream);
  hipMemsetAsync(embsum, 0, (size_t)G*256*4, stream);
  hipMemsetAsync(cnt,    0, (size_t)G*4, stream);

  int nblkN = (N + 255) / 256;
  int mblk  = (N + 63) / 64;
  int gblk  = (G + 63) / 64;
  int ablk  = (E + PA_TILE - 1) / PA_TILE;

  // CSR build: bucket histogram -> bucket scan -> partition -> fused per-bucket fill
  k_hist<<<ablk,256,0,stream>>>(ecol, bcnt, E);
  k_bscan<<<1,256,0,stream>>>(bcnt, bbase, bcur, E);
  k_passA<<<ablk,256,0,stream>>>(erow, ecol, bcur, ebuf, E);
  k_passB2<<<nb,256,0,stream>>>(ebuf, bbase, offs, dinv, csr, N, E, nb);
  k_cnt<<<nblkN,256,0,stream>>>(batch, cnt, N);

  // layer 1: aggregate-first (F=64), then GEMM 64->128 with fused relu+stats
  k_prep1<<<(N*16+255)/256,256,0,stream>>>((const float4*)x, dinv, (ushort4*)xs, N);
  k_agg1<<<(N+31)/32,256,0,stream>>>((const uint4*)xs, offs, csr, dinv, (uint4*)z1, N);
  k_gemm_mlp<64,128,false,false,true,true><<<dim3(mblk,1),256,0,stream>>>(z1, nullptr, W1, nullptr, nullptr, b1, h1, gs0, N);
  k_bnfin<<<1,256,0,stream>>>(gs0, 128, 1.0f/(float)N, g1, be1, sc1, sh1);

  // layer 2: fold bn1 affine + dinv into bf16 payload, aggregate (F=128), GEMM 128->256 + fused pool
  k_prep2<<<(N*32+255)/256,256,0,stream>>>((const uint2*)h1, dinv, (const float4*)sc1, (const float4*)sh1, (ushort4*)hs, N);
  k_agg2<<<(N+15)/16,256,0,stream>>>((const uint4*)hs, offs, csr, dinv, (uint4*)z2, N);
  k_gemm_pool<128,256><<<dim3(mblk,2),256,0,stream>>>(z2, W2, b2, batch, embsum, gs1, N);
  k_bnfin<<<1,256,0,stream>>>(gs1, 256, 1.0f/(float)N, g2, be2, sc2, sh2);

  // graph head
  k_emb<<<(G*64+255)/256,256,0,stream>>>(embsum, cnt, sc2, sh2, emb, G);
  k_gemm_mlp<456,256,true,false,false,false><<<dim3(gblk,2),256,0,stream>>>(emb, rdk, mW1, nullptr, nullptr, mb1, a1, gs2, G);
  k_bnfin<<<1,256,0,stream>>>(gs2, 256, 1.0f/(float)G, mg1, mbe1, sc3, sh3);
  k_gemm_mlp<256,128,false,true,false,false><<<dim3(gblk,1),256,0,stream>>>(a1, nullptr, mW2, sc3, sh3, mb2, a2, gs3, G);
  k_bnfin<<<1,256,0,stream>>>(gs3, 128, 1.0f/(float)G, mg2, mbe2, sc4, sh4);
  k_final<<<(G+3)/4,256,0,stream>>>(a2, sc4, sh4, mW3, mb3, (float*)d_out, G);
}